// Round 12
// baseline (10685.079 us; speedup 1.0000x reference)
//
#include <hip/hip_runtime.h>

#define B 64
#define TS 31          // T-1 steps
#define E 100
#define DY 200
#define DZ 500
#define V 32000
#define H 700
#define HP 704         // padded H (mult of 32) for MFMA K
#define H3 2100
#define XH 800         // xh row: x (cols 0..99) then h (cols 100..799)
#define SOS 2
#define OUT_PRED_OFF (33*B*H)   // outputs [33,64,700] then predictions [32,64,32000]
#define VCH 125        // v's per embed chunk
#define NVCH 256       // 256*125 = 32000
#define NPB 500        // pred col-units (V/64)
#define NPBP 512       // padded partials stride
#define NGU 264        // gate units: 33 n-tiles x 8 K-chunks

typedef unsigned short u16;
typedef __attribute__((ext_vector_type(8))) short short8;
typedef __attribute__((ext_vector_type(4))) float f32x4;

__device__ __forceinline__ float sigm(float x) { return 1.f / (1.f + __expf(-x)); }
__device__ __forceinline__ u16 f2b(float f) {
  union { float f; unsigned int u; } c; c.f = f;
  unsigned int u = c.u;
  u16 h = (u16)(u >> 16);
  unsigned int rem = u & 0xFFFFu;
  h += (u16)((rem > 0x8000u) || (rem == 0x8000u && (h & 1)));
  return h;
}

// ---------------- fallback: zero entire out (signature 0.4121094) ----------------
__global__ __launch_bounds__(256) void k_zero(float* __restrict__ out, long n) {
  long i0 = (long)blockIdx.x * 256 + threadIdx.x;
  long st = (long)gridDim.x * 256;
  for (long i = i0; i < n; i += st) out[i] = 0.f;
}

// ---------------- init: zeros, h0, x0, WT(f32), W_bf(bf16), h_bf, gh, cnt ----------------
__global__ __launch_bounds__(256) void k0_init(
    const float* __restrict__ z, const float* __restrict__ labels,
    const float* __restrict__ W_fc, const float* __restrict__ b_fc,
    const float* __restrict__ embed, const float* __restrict__ W_ih,
    const float* __restrict__ W_hh, const float* __restrict__ W_out,
    float* __restrict__ out, float* __restrict__ xhA, float* __restrict__ WT,
    u16* __restrict__ W_bf, u16* __restrict__ h_bf, float* __restrict__ gh,
    int* __restrict__ cnt)
{
  long i0 = (long)blockIdx.x * 256 + threadIdx.x;
  long st = (long)gridDim.x * 256;
  if (i0 == 0) *cnt = 0;                     // reset spin-barrier counter every call
  for (long i = i0; i < (long)B * V; i += st) out[OUT_PRED_OFF + i] = 0.f;
  for (long i = i0; i < (long)B * H; i += st) out[B * H + i] = 0.f;
  for (long i = i0; i < (long)B * H; i += st) {
    int b = (int)(i / H), j = (int)(i % H);
    float v = (j < DY) ? (1.f - labels[b]) * W_fc[j] + b_fc[j]
                       : z[b * DZ + (j - DY)];
    xhA[b * XH + 100 + j] = v;
    out[i] = v;
  }
  for (long i = i0; i < (long)B * E; i += st) {
    int b = (int)(i / E), e = (int)(i % E);
    xhA[b * XH + e] = embed[SOS * E + e];
  }
  for (long i = i0; i < (long)B * HP; i += st) h_bf[i] = 0;
  for (long i = i0; i < (long)B * H3; i += st) gh[i] = 0.f;
  for (long i = i0; i < (long)XH * H3; i += st) {
    int k = (int)(i / H3), g = (int)(i % H3);
    WT[i] = (k < E) ? W_ih[(long)g * E + k] : W_hh[(long)g * H + (k - E)];
  }
  for (long i = i0; i < (long)V * HP; i += st) {
    int v = (int)(i / HP), j = (int)(i % HP);
    W_bf[i] = (j < H) ? f2b(W_out[(long)v * H + j]) : (u16)0;
  }
}

// ---------------- persistent kernel: all 31 steps, 4 phases + grid spin-barriers ----------------
__global__ __launch_bounds__(256) void kmain(
    const float* __restrict__ WT, float* __restrict__ gi, float* __restrict__ gh,
    float* __restrict__ S, float* __restrict__ part_m, float* __restrict__ part_z,
    const u16* __restrict__ W_bf, u16* __restrict__ h_bf,
    float* __restrict__ xhA, float* __restrict__ xhB,
    float* __restrict__ out, const float* __restrict__ gu,
    const float* __restrict__ b_ih, const float* __restrict__ b_hh,
    const float* __restrict__ b_out, const float* __restrict__ embed,
    int* cnt)
{
  const int bid = blockIdx.x, tid = threadIdx.x;
  __shared__ union {
    float xs[64][100];                                   // phase A staging
    struct { float lm[64][4]; float lz[64][4]; } pc;     // phase C partial combine
    struct { float Ms[64]; float Is[64]; float ys[64][VCH]; } pd;  // phase D
  } sh;

  int bar = 0;
  // grid barrier: co-resident 256 blocks (1/CU); counter reset by k0_init
  #define GBAR() do {                                                              \
      ++bar; __syncthreads();                                                      \
      if (tid == 0) {                                                              \
        __threadfence();                                                           \
        atomicAdd(cnt, 1);                                                         \
        while (__hip_atomic_load(cnt, __ATOMIC_RELAXED,                            \
                                 __HIP_MEMORY_SCOPE_AGENT) < bar * 256)            \
          __builtin_amdgcn_s_sleep(4);                                             \
      }                                                                            \
      __syncthreads(); __threadfence();                                            \
    } while (0)

  for (int t = 0; t < TS; ++t) {
    const float* xin  = (t & 1) ? xhB : xhA;
    float*       xout = (t & 1) ? xhA : xhB;
    float*       pred = out + OUT_PRED_OFF + (size_t)(1 + t) * B * V;
    const float* gut  = gu + (size_t)t * B * V;
    float*       outh = out + (size_t)(2 + t) * B * H;

    // ---- Phase A: gates GEMM (264 units; c==0 -> gi store, else gh atomic) ----
    for (int u = bid; u < NGU; u += 256) {
      int nt = u % 33, c = u / 33;
      for (int i = tid; i < 6400; i += 256) {
        int b = i / 100, kk = i % 100;
        sh.xs[b][kk] = xin[b * XH + c * 100 + kk];
      }
      __syncthreads();
      int n = nt * 64 + (tid & 63);
      int bq = tid >> 6;
      if (n < H3) {
        float acc[16];
        #pragma unroll
        for (int bb = 0; bb < 16; ++bb) acc[bb] = 0.f;
        for (int kk = 0; kk < 100; kk += 4) {
          const float* wr = &WT[(size_t)(c * 100 + kk) * H3 + n];
          float w0 = wr[0], w1 = wr[H3], w2 = wr[2 * H3], w3 = wr[3 * H3];
          #pragma unroll
          for (int bb = 0; bb < 16; ++bb) {
            float4 x = *reinterpret_cast<const float4*>(&sh.xs[bq * 16 + bb][kk]);
            acc[bb] += x.x * w0 + x.y * w1 + x.z * w2 + x.w * w3;
          }
        }
        if (c == 0) {
          float bi = b_ih[n];
          #pragma unroll
          for (int bb = 0; bb < 16; ++bb) gi[(size_t)(bq * 16 + bb) * H3 + n] = acc[bb] + bi;
        } else {
          #pragma unroll
          for (int bb = 0; bb < 16; ++bb)
            atomicAdd(&gh[(size_t)(bq * 16 + bb) * H3 + n], acc[bb]);
        }
      }
      __syncthreads();
    }
    GBAR();

    // ---- Phase B: gates + h update; read-then-zero gh; zero xout x-part ----
    {
      int i = bid * 256 + tid;
      if (i < B * H) {
        int b = i / H, j = i % H;
        size_t g0 = (size_t)b * H3 + j;
        float ir = gi[g0], iz = gi[g0 + H], in_ = gi[g0 + 2 * H];
        float hr = gh[g0] + b_hh[j];
        float hz = gh[g0 + H] + b_hh[H + j];
        float hn = gh[g0 + 2 * H] + b_hh[2 * H + j];
        gh[g0] = 0.f; gh[g0 + H] = 0.f; gh[g0 + 2 * H] = 0.f;   // ready for next step
        float hprev = xin[b * XH + 100 + j];
        float r  = sigm(ir + hr);
        float zt = sigm(iz + hz);
        float nn = tanhf(in_ + r * hn);
        float hv = (1.f - zt) * nn + zt * hprev;
        xout[b * XH + 100 + j] = hv;
        outh[i] = hv;
        h_bf[b * HP + j] = f2b(hv);
        if (j < 100) xout[b * XH + j] = 0.f;
      }
    }
    GBAR();

    // ---- Phase C: pred MFMA GEMM + gumbel + per-unit softmax partials ----
    for (int u = bid; u < NPB; u += 256) {
      int wave = tid >> 6, lane = tid & 63;
      int l15 = lane & 15;
      int col = u * 64 + wave * 16 + l15;
      int kq = (lane >> 4) << 3;
      f32x4 acc[4];
      #pragma unroll
      for (int q = 0; q < 4; ++q) acc[q] = f32x4{0.f, 0.f, 0.f, 0.f};
      const u16* wp = W_bf + (size_t)col * HP + kq;
      const u16* hp = h_bf + kq;
      for (int k = 0; k < HP; k += 32) {
        short8 bv = *reinterpret_cast<const short8*>(wp + k);
        #pragma unroll
        for (int rt = 0; rt < 4; ++rt) {
          short8 a = *reinterpret_cast<const short8*>(hp + (size_t)(rt * 16 + l15) * HP + k);
          acc[rt] = __builtin_amdgcn_mfma_f32_16x16x32_bf16(a, bv, acc[rt], 0, 0, 0);
        }
      }
      float bo = b_out[col];
      #pragma unroll
      for (int rt = 0; rt < 4; ++rt) {
        #pragma unroll
        for (int r = 0; r < 4; ++r) {
          int brow = rt * 16 + ((lane >> 4) << 2) + r;  // C/D: col=lane&15, row=(lane>>4)*4+r
          float pv = acc[rt][r] + bo;
          size_t off = (size_t)brow * V + col;
          pred[off] = pv;
          float uu = gut[off];
          float g = -logf(-logf(uu + 1e-10f) + 1e-10f);
          float s = pv + g;
          S[off] = s;
          float vm = s, vz = 1.f;
          #pragma unroll
          for (int msk = 1; msk < 16; msk <<= 1) {
            float om = __shfl_xor(vm, msk);
            float oz = __shfl_xor(vz, msk);
            float nm = fmaxf(vm, om);
            vz = vz * __expf(vm - nm) + oz * __expf(om - nm);
            vm = nm;
          }
          if (l15 == 0) { sh.pc.lm[brow][wave] = vm; sh.pc.lz[brow][wave] = vz; }
        }
      }
      __syncthreads();
      if (tid < 64) {
        int b = tid;
        float m0 = fmaxf(fmaxf(sh.pc.lm[b][0], sh.pc.lm[b][1]),
                         fmaxf(sh.pc.lm[b][2], sh.pc.lm[b][3]));
        float zz = sh.pc.lz[b][0] * __expf(sh.pc.lm[b][0] - m0)
                 + sh.pc.lz[b][1] * __expf(sh.pc.lm[b][1] - m0)
                 + sh.pc.lz[b][2] * __expf(sh.pc.lm[b][2] - m0)
                 + sh.pc.lz[b][3] * __expf(sh.pc.lm[b][3] - m0);
        part_m[(size_t)b * NPBP + u] = m0;
        part_z[(size_t)b * NPBP + u] = zz;
      }
      __syncthreads();
    }
    GBAR();

    // ---- Phase D: combine partials, y inline, embed GEMM, atomic x ----
    {
      int v0 = bid * VCH;
      {
        int b = tid >> 2, q = tid & 3;
        const float* pm = part_m + (size_t)b * NPBP;
        const float* pz = part_z + (size_t)b * NPBP;
        float m = -1e30f;
        for (int i = q; i < NPB; i += 4) m = fmaxf(m, pm[i]);
        m = fmaxf(m, __shfl_xor(m, 1));
        m = fmaxf(m, __shfl_xor(m, 2));
        float zz = 0.f;
        for (int i = q; i < NPB; i += 4) zz += pz[i] * __expf(pm[i] - m);
        zz += __shfl_xor(zz, 1);
        zz += __shfl_xor(zz, 2);
        if (q == 0) { sh.pd.Ms[b] = m; sh.pd.Is[b] = 2.f / zz; }  // y/GAMMA
      }
      __syncthreads();
      for (int i = tid; i < 64 * VCH; i += 256) {
        int b = i / VCH, vv = i % VCH;
        sh.pd.ys[b][vv] = __expf(S[(size_t)b * V + v0 + vv] - sh.pd.Ms[b]) * sh.pd.Is[b];
      }
      __syncthreads();
      int e = tid & 127, bh = tid >> 7;
      if (e < E) {
        float acc[32];
        #pragma unroll
        for (int bb = 0; bb < 32; ++bb) acc[bb] = 0.f;
        for (int vv = 0; vv < VCH; ++vv) {
          float w = embed[(size_t)(v0 + vv) * E + e];
          #pragma unroll
          for (int bb = 0; bb < 32; ++bb) acc[bb] += sh.pd.ys[bh * 32 + bb][vv] * w;
        }
        #pragma unroll
        for (int bb = 0; bb < 32; ++bb)
          atomicAdd(&xout[(size_t)(bh * 32 + bb) * XH + e], acc[bb]);
      }
      __syncthreads();
    }
    GBAR();
  }
  #undef GBAR
}

extern "C" void kernel_launch(void* const* d_in, const int* in_sizes, int n_in,
                              void* d_out, int out_size, void* d_ws, size_t ws_size,
                              hipStream_t stream) {
  (void)ws_size;
  float* out = (float*)d_out;

  static const long lsz[12] = {32000, 64, 200, 200, 3200000, 210000, 1470000,
                               2100, 2100, 22400000, 32000, 63488000};
  static const int dictP[12]    = {0, 1, 2, 3, 4, 5, 6, 7, 8, 9, 10, 11};
  static const int alpha14P[12] = {13, 10, 0, 4, 8, 2, 1, 6, 5, 3, 7, 9};
  static const int alpha12P[12] = {11, 10, 0, 4, 8, 2, 1, 6, 5, 3, 7, 9};
  auto okperm = [&](const int* p) -> bool {
    for (int i = 0; i < 12; ++i) {
      if (p[i] >= n_in) return false;
      if ((long)in_sizes[p[i]] != lsz[i]) return false;
    }
    return true;
  };
  const int* P = nullptr;
  if (okperm(dictP)) P = dictP;
  else if (okperm(alpha14P)) P = alpha14P;
  else if (okperm(alpha12P)) P = alpha12P;
  if (!P) { k_zero<<<2048, 256, 0, stream>>>(out, (long)out_size); return; }

  const float* z      = (const float*)d_in[P[0]];
  const float* labels = (const float*)d_in[P[1]];
  const float* W_fc   = (const float*)d_in[P[2]];
  const float* b_fc   = (const float*)d_in[P[3]];
  const float* embed  = (const float*)d_in[P[4]];
  const float* W_ih   = (const float*)d_in[P[5]];
  const float* W_hh   = (const float*)d_in[P[6]];
  const float* b_ih   = (const float*)d_in[P[7]];
  const float* b_hh   = (const float*)d_in[P[8]];
  const float* W_out  = (const float*)d_in[P[9]];
  const float* b_out  = (const float*)d_in[P[10]];
  const float* gu     = (const float*)d_in[P[11]];

  char* w = (char*)d_ws;
  auto alloc = [&](size_t bytes) { char* p = w; w += (bytes + 255) & ~(size_t)255; return p; };
  float* xhA    = (float*)alloc((size_t)B * XH * 4);
  float* xhB    = (float*)alloc((size_t)B * XH * 4);
  float* WT     = (float*)alloc((size_t)XH * H3 * 4);
  float* gi     = (float*)alloc((size_t)B * H3 * 4);
  float* gh     = (float*)alloc((size_t)B * H3 * 4);
  float* S      = (float*)alloc((size_t)B * V * 4);
  float* part_m = (float*)alloc((size_t)B * NPBP * 4);
  float* part_z = (float*)alloc((size_t)B * NPBP * 4);
  u16*  W_bf    = (u16*)alloc((size_t)V * HP * 2);
  u16*  h_bf    = (u16*)alloc((size_t)B * HP * 2);
  int*  cnt     = (int*)alloc(256);

  k0_init<<<2048, 256, 0, stream>>>(z, labels, W_fc, b_fc, embed, W_ih, W_hh, W_out,
                                    out, xhA, WT, W_bf, h_bf, gh, cnt);
  kmain<<<256, 256, 0, stream>>>(WT, gi, gh, S, part_m, part_z, W_bf, h_bf,
                                 xhA, xhB, out, gu, b_ih, b_hh, b_out, embed, cnt);
}